// Round 15
// baseline (46.271 us; speedup 1.0000x reference)
//
#include <hip/hip_runtime.h>
#include <hip/hip_fp16.h>

// DeepseekV4HashRouter: B=4,S=4096,D=2048,E=256,K=8,V=128000
#define DIM    2048
#define NEXP   256
#define TOPK   8
#define RSCALE 2.5f
#define WPT    4          // waves (tokens) per 256-thread block
#define WSCALE 64.0f      // weight pre-scale into e4m3 normal range
#define INV_WSCALE 0.015625f

typedef float f2 __attribute__((ext_vector_type(2)));
typedef float f4 __attribute__((ext_vector_type(4)));   // native vec for NT ops

// fp32 -> fp8 e4m3 (x64), PERMUTED so router's lane-contiguous uint4 load
// matches lane-contiguous hidden float4 loads:
//   w8p[e][u=j*64+lane].dword[c] = w[e][j*1024 + c*256 + lane*4 .. +4]
__global__ __launch_bounds__(256) void convert_weight_fp8p(
    const float* __restrict__ w, uint4* __restrict__ w8p) {
    const int t    = blockIdx.x * blockDim.x + threadIdx.x;  // 0 .. E*128-1
    const int e    = t >> 7;
    const int u    = t & 127;        // j*64 + lane
    const int j    = u >> 6;
    const int lane = u & 63;
    const f4* src = reinterpret_cast<const f4*>(w) + (size_t)e * 512 + j * 256 + lane;
    uint4 o;
    unsigned int* od = reinterpret_cast<unsigned int*>(&o);
#pragma unroll
    for (int c = 0; c < 4; ++c) {
        const f4 f = __builtin_nontemporal_load(&src[c * 64]);
        int r = 0;
        r = __builtin_amdgcn_cvt_pk_fp8_f32(f.x * WSCALE, f.y * WSCALE, r, false);
        r = __builtin_amdgcn_cvt_pk_fp8_f32(f.z * WSCALE, f.w * WSCALE, r, true);
        od[c] = (unsigned int)r;
    }
    w8p[(size_t)e * 128 + u] = o;   // cached store: re-read by router soon
}

// One 64-lane wave per token; permuted fp8 weight rows (L2-resident, cached);
// streaming hidden/out marked non-temporal to avoid evicting the weight table.
__global__ __launch_bounds__(256) void router_fp8(
    const float* __restrict__ hidden,   // [N, D] fp32
    const int* __restrict__ token_ids,  // [N] int32
    const uint4* __restrict__ w8,       // [E, D] fp8 permuted
    const int* __restrict__ tid2eid,    // [V, K] int32
    float* __restrict__ out,            // probs [N,E] then map [N,E]
    int N) {
    const int lane = threadIdx.x & 63;
    const int n = blockIdx.x * WPT + (threadIdx.x >> 6);
    if (n >= N) return;

    // Wave-uniform token id / expert ids -> SGPRs.
    const int tid = __builtin_amdgcn_readfirstlane(token_ids[n]);
    const int* er = tid2eid + (size_t)tid * TOPK;
    int eidx[TOPK];
#pragma unroll
    for (int k = 0; k < TOPK; ++k)
        eidx[k] = __builtin_amdgcn_readfirstlane(er[k]);

    const uint4* wb[TOPK];
#pragma unroll
    for (int k = 0; k < TOPK; ++k)
        wb[k] = w8 + (size_t)eidx[k] * (DIM / 16);

    const f4* h4 = reinterpret_cast<const f4*>(hidden + (size_t)n * DIM);

    float acc[TOPK] = {0.f, 0.f, 0.f, 0.f, 0.f, 0.f, 0.f, 0.f};

#pragma unroll
    for (int j = 0; j < 2; ++j) {
        // 8 independent 16B weight loads (distinct SGPR bases, lane-contiguous,
        // CACHED — the 512KB table must stay L2-resident).
        uint4 wv[TOPK];
#pragma unroll
        for (int k = 0; k < TOPK; ++k) wv[k] = wb[k][j * 64 + lane];
        // Hidden: 4 lane-contiguous float4 loads, NON-TEMPORAL (used once).
        f4 hv[4];
#pragma unroll
        for (int i = 0; i < 4; ++i)
            hv[i] = __builtin_nontemporal_load(&h4[j * 256 + i * 64 + lane]);

#pragma unroll
        for (int k = 0; k < TOPK; ++k) {
            const unsigned int* wu = reinterpret_cast<const unsigned int*>(&wv[k]);
            float s = acc[k];
#pragma unroll
            for (int c = 0; c < 4; ++c) {
                const int u = (int)wu[c];
                const f2 a = __builtin_amdgcn_cvt_pk_f32_fp8(u, false);
                const f2 b = __builtin_amdgcn_cvt_pk_f32_fp8(u, true);
                s = fmaf(hv[c].x, a.x, s);
                s = fmaf(hv[c].y, a.y, s);
                s = fmaf(hv[c].z, b.x, s);
                s = fmaf(hv[c].w, b.y, s);
            }
            acc[k] = s;
        }
    }

    // Tournament reduce: 8 values/lane -> 1 value/lane in 7 shfls + 3 butterfly.
    const int b0 = lane & 1, b1 = (lane >> 1) & 1, b2 = (lane >> 2) & 1;
    float v4[4];
#pragma unroll
    for (int k = 0; k < 4; ++k) {
        const float send = b0 ? acc[k] : acc[k + 4];
        const float recv = __shfl_xor(send, 1, 64);
        v4[k] = (b0 ? acc[k + 4] : acc[k]) + recv;
    }
    float v2[2];
#pragma unroll
    for (int j = 0; j < 2; ++j) {
        const float send = b1 ? v4[j] : v4[j + 2];
        const float recv = __shfl_xor(send, 2, 64);
        v2[j] = (b1 ? v4[j + 2] : v4[j]) + recv;
    }
    {
        const float send = b2 ? v2[0] : v2[1];
        const float recv = __shfl_xor(send, 4, 64);
        v2[0] = (b2 ? v2[1] : v2[0]) + recv;
    }
    float v = v2[0];
    v += __shfl_xor(v, 8, 64);
    v += __shfl_xor(v, 16, 64);
    v += __shfl_xor(v, 32, 64);
    v *= INV_WSCALE;  // undo e4m3 pre-scale
    // Lane l holds logit of expert slot e(l) = 4*b0 + 2*b1 + b2.

    const float sp = fmaxf(v, 0.0f) + log1pf(expf(-fabsf(v)));
    const float score = sqrtf(sp);

    // Slot k lives in lane bit-rev3(k).
    float sc[TOPK];
    float denom = 0.0f;
#pragma unroll
    for (int k = 0; k < TOPK; ++k) {
        const int src = ((k >> 2) & 1) | (k & 2) | ((k & 1) << 2);
        sc[k] = __shfl(score, src, 64);
        denom += sc[k];
    }
    const float inv = RSCALE / fmaxf(denom, 1e-12f);

    // Dense vectorized write: lane l owns experts 4l..4l+3. Non-temporal.
    f4 p, m;
#pragma unroll
    for (int c = 0; c < 4; ++c) {
        const int e = lane * 4 + c;
        float pv = 0.0f, mv = 0.0f;
#pragma unroll
        for (int k = 0; k < TOPK; ++k) {
            if (eidx[k] == e) { pv = sc[k] * inv; mv = 1.0f; }
        }
        p[c] = pv; m[c] = mv;
    }
    __builtin_nontemporal_store(p, reinterpret_cast<f4*>(out + (size_t)n * NEXP) + lane);
    __builtin_nontemporal_store(m, reinterpret_cast<f4*>(out + (size_t)(N + n) * NEXP) + lane);
}

// Fallback (no workspace): fp32 gather, one wave per token.
__global__ __launch_bounds__(256) void router_fp32(
    const float* __restrict__ hidden, const int* __restrict__ token_ids,
    const float* __restrict__ weight, const int* __restrict__ tid2eid,
    float* __restrict__ out, int N) {
    const int lane = threadIdx.x & 63;
    const int n = blockIdx.x * 4 + (threadIdx.x >> 6);
    if (n >= N) return;
    const int tid = token_ids[n];
    const int* er = tid2eid + (size_t)tid * TOPK;
    int eidx[TOPK];
#pragma unroll
    for (int k = 0; k < TOPK; ++k) eidx[k] = er[k];
    const float4* h4 = reinterpret_cast<const float4*>(hidden + (size_t)n * DIM);
    float acc[TOPK] = {};
#pragma unroll
    for (int j = 0; j < 4; ++j) {
        const float4 a = h4[j * 128 + lane * 2];
        const float4 b = h4[j * 128 + lane * 2 + 1];
#pragma unroll
        for (int k = 0; k < TOPK; ++k) {
            const float4* wr = reinterpret_cast<const float4*>(weight + (size_t)eidx[k] * DIM);
            const float4 wa = wr[j * 128 + lane * 2];
            const float4 wb = wr[j * 128 + lane * 2 + 1];
            acc[k] += a.x * wa.x + a.y * wa.y + a.z * wa.z + a.w * wa.w
                    + b.x * wb.x + b.y * wb.y + b.z * wb.z + b.w * wb.w;
        }
    }
#pragma unroll
    for (int k = 0; k < TOPK; ++k) {
        float v = acc[k];
#pragma unroll
        for (int m = 1; m < 64; m <<= 1) v += __shfl_xor(v, m, 64);
        acc[k] = v;
    }
    float sval = 0.0f;
    if (lane < TOPK) {
        const float sp = fmaxf(acc[lane], 0.0f) + log1pf(expf(-fabsf(acc[lane])));
        sval = sqrtf(sp);
    }
    float sc[TOPK]; float denom = 0.0f;
#pragma unroll
    for (int k = 0; k < TOPK; ++k) { sc[k] = __shfl(sval, k, 64); denom += sc[k]; }
    const float inv = RSCALE / fmaxf(denom, 1e-12f);
    float4 p, mv;
    float* pp = reinterpret_cast<float*>(&p);
    float* mm = reinterpret_cast<float*>(&mv);
#pragma unroll
    for (int c = 0; c < 4; ++c) {
        const int e = lane * 4 + c;
        float pv = 0.0f, fv = 0.0f;
#pragma unroll
        for (int k = 0; k < TOPK; ++k)
            if (eidx[k] == e) { pv = sc[k] * inv; fv = 1.0f; }
        pp[c] = pv; mm[c] = fv;
    }
    reinterpret_cast<float4*>(out + (size_t)n * NEXP)[lane] = p;
    reinterpret_cast<float4*>(out + (size_t)(N + n) * NEXP)[lane] = mv;
}

extern "C" void kernel_launch(void* const* d_in, const int* in_sizes, int n_in,
                              void* d_out, int out_size, void* d_ws, size_t ws_size,
                              hipStream_t stream) {
    const float* hidden    = (const float*)d_in[0];
    const int*   token_ids = (const int*)d_in[1];   // int64 in ref -> int32 here
    const float* weight    = (const float*)d_in[2];
    const int*   tid2eid   = (const int*)d_in[3];
    float* out = (float*)d_out;
    const int N = in_sizes[1];  // B*S tokens

    const int nblocks = (N + WPT - 1) / WPT;
    const size_t need = (size_t)NEXP * DIM;  // 512 KiB of fp8
    if (ws_size >= need) {
        uint4* w8 = (uint4*)d_ws;
        const int nt = NEXP * 128;  // one thread per uint4
        convert_weight_fp8p<<<nt / 256, 256, 0, stream>>>(weight, w8);
        router_fp8<<<nblocks, 256, 0, stream>>>(hidden, token_ids,
                                                (const uint4*)w8, tid2eid, out, N);
    } else {
        router_fp32<<<nblocks, 256, 0, stream>>>(hidden, token_ids, weight,
                                                 tid2eid, out, N);
    }
}

// Round 16
// 38.451 us; speedup vs baseline: 1.2034x; 1.2034x over previous
//
#include <hip/hip_runtime.h>
#include <hip/hip_fp16.h>

// DeepseekV4HashRouter: B=4,S=4096,D=2048,E=256,K=8,V=128000
#define DIM    2048
#define NEXP   256
#define TOPK   8
#define RSCALE 2.5f
#define WPT    4          // waves (tokens) per 256-thread block
#define WSCALE 64.0f      // weight pre-scale into e4m3 normal range
#define INV_WSCALE 0.015625f

typedef float f2 __attribute__((ext_vector_type(2)));

// fp32 -> fp8 e4m3 (x64), PERMUTED so router's lane-contiguous uint4 load
// matches lane-contiguous hidden float4 loads:
//   w8p[e][u=j*64+lane].dword[c] = w[e][j*1024 + c*256 + lane*4 .. +4]
__global__ __launch_bounds__(256) void convert_weight_fp8p(
    const float* __restrict__ w, uint4* __restrict__ w8p) {
    const int t    = blockIdx.x * blockDim.x + threadIdx.x;  // 0 .. E*128-1
    const int e    = t >> 7;
    const int u    = t & 127;        // j*64 + lane
    const int j    = u >> 6;
    const int lane = u & 63;
    const float4* src = reinterpret_cast<const float4*>(w) + (size_t)e * 512 + j * 256 + lane;
    uint4 o;
    unsigned int* od = reinterpret_cast<unsigned int*>(&o);
#pragma unroll
    for (int c = 0; c < 4; ++c) {
        const float4 f = src[c * 64];
        int r = 0;
        r = __builtin_amdgcn_cvt_pk_fp8_f32(f.x * WSCALE, f.y * WSCALE, r, false);
        r = __builtin_amdgcn_cvt_pk_fp8_f32(f.z * WSCALE, f.w * WSCALE, r, true);
        od[c] = (unsigned int)r;
    }
    w8p[(size_t)e * 128 + u] = o;
}

// One 64-lane wave per token; permuted fp8 weight rows; all vmem accesses
// lane-contiguous (hidden 1KB/instr, weight 1KB/instr); SGPR expert bases.
__global__ __launch_bounds__(256) void router_fp8(
    const float* __restrict__ hidden,   // [N, D] fp32
    const int* __restrict__ token_ids,  // [N] int32
    const uint4* __restrict__ w8,       // [E, D] fp8 permuted
    const int* __restrict__ tid2eid,    // [V, K] int32
    float* __restrict__ out,            // probs [N,E] then map [N,E]
    int N) {
    const int lane = threadIdx.x & 63;
    const int n = blockIdx.x * WPT + (threadIdx.x >> 6);
    if (n >= N) return;

    // Wave-uniform token id / expert ids -> SGPRs.
    const int tid = __builtin_amdgcn_readfirstlane(token_ids[n]);
    const int* er = tid2eid + (size_t)tid * TOPK;
    int eidx[TOPK];
#pragma unroll
    for (int k = 0; k < TOPK; ++k)
        eidx[k] = __builtin_amdgcn_readfirstlane(er[k]);

    const uint4* wb[TOPK];
#pragma unroll
    for (int k = 0; k < TOPK; ++k)
        wb[k] = w8 + (size_t)eidx[k] * (DIM / 16);

    const float4* h4 = reinterpret_cast<const float4*>(hidden + (size_t)n * DIM);

    float acc[TOPK] = {0.f, 0.f, 0.f, 0.f, 0.f, 0.f, 0.f, 0.f};

#pragma unroll
    for (int j = 0; j < 2; ++j) {
        // 8 independent 16B weight loads (distinct SGPR bases, lane-contiguous).
        uint4 wv[TOPK];
#pragma unroll
        for (int k = 0; k < TOPK; ++k) wv[k] = wb[k][j * 64 + lane];
        // Hidden: 4 lane-contiguous float4 loads; lane's elems
        // {j*1024 + i*256 + lane*4 .. +4} match weight dword i (permuted).
        float4 hv[4];
#pragma unroll
        for (int i = 0; i < 4; ++i) hv[i] = h4[j * 256 + i * 64 + lane];

#pragma unroll
        for (int k = 0; k < TOPK; ++k) {
            const unsigned int* wu = reinterpret_cast<const unsigned int*>(&wv[k]);
            float s = acc[k];
#pragma unroll
            for (int c = 0; c < 4; ++c) {
                const int u = (int)wu[c];
                const f2 a = __builtin_amdgcn_cvt_pk_f32_fp8(u, false);
                const f2 b = __builtin_amdgcn_cvt_pk_f32_fp8(u, true);
                s = fmaf(hv[c].x, a.x, s);
                s = fmaf(hv[c].y, a.y, s);
                s = fmaf(hv[c].z, b.x, s);
                s = fmaf(hv[c].w, b.y, s);
            }
            acc[k] = s;
        }
    }

    // Tournament reduce: 8 values/lane -> 1 value/lane in 7 shfls + 3 butterfly.
    const int b0 = lane & 1, b1 = (lane >> 1) & 1, b2 = (lane >> 2) & 1;
    float v4[4];
#pragma unroll
    for (int k = 0; k < 4; ++k) {
        const float send = b0 ? acc[k] : acc[k + 4];
        const float recv = __shfl_xor(send, 1, 64);
        v4[k] = (b0 ? acc[k + 4] : acc[k]) + recv;
    }
    float v2[2];
#pragma unroll
    for (int j = 0; j < 2; ++j) {
        const float send = b1 ? v4[j] : v4[j + 2];
        const float recv = __shfl_xor(send, 2, 64);
        v2[j] = (b1 ? v4[j + 2] : v4[j]) + recv;
    }
    {
        const float send = b2 ? v2[0] : v2[1];
        const float recv = __shfl_xor(send, 4, 64);
        v2[0] = (b2 ? v2[1] : v2[0]) + recv;
    }
    float v = v2[0];
    v += __shfl_xor(v, 8, 64);
    v += __shfl_xor(v, 16, 64);
    v += __shfl_xor(v, 32, 64);
    v *= INV_WSCALE;  // undo e4m3 pre-scale
    // Lane l holds logit of expert slot e(l) = 4*b0 + 2*b1 + b2.

    const float sp = fmaxf(v, 0.0f) + log1pf(expf(-fabsf(v)));
    const float score = sqrtf(sp);

    // Slot k lives in lane bit-rev3(k).
    float sc[TOPK];
    float denom = 0.0f;
#pragma unroll
    for (int k = 0; k < TOPK; ++k) {
        const int src = ((k >> 2) & 1) | (k & 2) | ((k & 1) << 2);
        sc[k] = __shfl(score, src, 64);
        denom += sc[k];
    }
    const float inv = RSCALE / fmaxf(denom, 1e-12f);

    // Dense vectorized write: lane l owns experts 4l..4l+3.
    float4 p, m;
    float* pp = reinterpret_cast<float*>(&p);
    float* mm = reinterpret_cast<float*>(&m);
#pragma unroll
    for (int c = 0; c < 4; ++c) {
        const int e = lane * 4 + c;
        float pv = 0.0f, mv = 0.0f;
#pragma unroll
        for (int k = 0; k < TOPK; ++k) {
            if (eidx[k] == e) { pv = sc[k] * inv; mv = 1.0f; }
        }
        pp[c] = pv; mm[c] = mv;
    }
    reinterpret_cast<float4*>(out + (size_t)n * NEXP)[lane] = p;
    reinterpret_cast<float4*>(out + (size_t)(N + n) * NEXP)[lane] = m;
}

// Fallback (no workspace): fp32 gather, one wave per token.
__global__ __launch_bounds__(256) void router_fp32(
    const float* __restrict__ hidden, const int* __restrict__ token_ids,
    const float* __restrict__ weight, const int* __restrict__ tid2eid,
    float* __restrict__ out, int N) {
    const int lane = threadIdx.x & 63;
    const int n = blockIdx.x * 4 + (threadIdx.x >> 6);
    if (n >= N) return;
    const int tid = token_ids[n];
    const int* er = tid2eid + (size_t)tid * TOPK;
    int eidx[TOPK];
#pragma unroll
    for (int k = 0; k < TOPK; ++k) eidx[k] = er[k];
    const float4* h4 = reinterpret_cast<const float4*>(hidden + (size_t)n * DIM);
    float acc[TOPK] = {};
#pragma unroll
    for (int j = 0; j < 4; ++j) {
        const float4 a = h4[j * 128 + lane * 2];
        const float4 b = h4[j * 128 + lane * 2 + 1];
#pragma unroll
        for (int k = 0; k < TOPK; ++k) {
            const float4* wr = reinterpret_cast<const float4*>(weight + (size_t)eidx[k] * DIM);
            const float4 wa = wr[j * 128 + lane * 2];
            const float4 wb = wr[j * 128 + lane * 2 + 1];
            acc[k] += a.x * wa.x + a.y * wa.y + a.z * wa.z + a.w * wa.w
                    + b.x * wb.x + b.y * wb.y + b.z * wb.z + b.w * wb.w;
        }
    }
#pragma unroll
    for (int k = 0; k < TOPK; ++k) {
        float v = acc[k];
#pragma unroll
        for (int m = 1; m < 64; m <<= 1) v += __shfl_xor(v, m, 64);
        acc[k] = v;
    }
    float sval = 0.0f;
    if (lane < TOPK) {
        const float sp = fmaxf(acc[lane], 0.0f) + log1pf(expf(-fabsf(acc[lane])));
        sval = sqrtf(sp);
    }
    float sc[TOPK]; float denom = 0.0f;
#pragma unroll
    for (int k = 0; k < TOPK; ++k) { sc[k] = __shfl(sval, k, 64); denom += sc[k]; }
    const float inv = RSCALE / fmaxf(denom, 1e-12f);
    float4 p, mv;
    float* pp = reinterpret_cast<float*>(&p);
    float* mm = reinterpret_cast<float*>(&mv);
#pragma unroll
    for (int c = 0; c < 4; ++c) {
        const int e = lane * 4 + c;
        float pv = 0.0f, fv = 0.0f;
#pragma unroll
        for (int k = 0; k < TOPK; ++k)
            if (eidx[k] == e) { pv = sc[k] * inv; fv = 1.0f; }
        pp[c] = pv; mm[c] = fv;
    }
    reinterpret_cast<float4*>(out + (size_t)n * NEXP)[lane] = p;
    reinterpret_cast<float4*>(out + (size_t)(N + n) * NEXP)[lane] = mv;
}

extern "C" void kernel_launch(void* const* d_in, const int* in_sizes, int n_in,
                              void* d_out, int out_size, void* d_ws, size_t ws_size,
                              hipStream_t stream) {
    const float* hidden    = (const float*)d_in[0];
    const int*   token_ids = (const int*)d_in[1];   // int64 in ref -> int32 here
    const float* weight    = (const float*)d_in[2];
    const int*   tid2eid   = (const int*)d_in[3];
    float* out = (float*)d_out;
    const int N = in_sizes[1];  // B*S tokens

    const int nblocks = (N + WPT - 1) / WPT;
    const size_t need = (size_t)NEXP * DIM;  // 512 KiB of fp8
    if (ws_size >= need) {
        uint4* w8 = (uint4*)d_ws;
        const int nt = NEXP * 128;  // one thread per uint4
        convert_weight_fp8p<<<nt / 256, 256, 0, stream>>>(weight, w8);
        router_fp8<<<nblocks, 256, 0, stream>>>(hidden, token_ids,
                                                (const uint4*)w8, tid2eid, out, N);
    } else {
        router_fp32<<<nblocks, 256, 0, stream>>>(hidden, token_ids, weight,
                                                 tid2eid, out, N);
    }
}